// Round 12
// baseline (338.871 us; speedup 1.0000x reference)
//
#include <hip/hip_runtime.h>
#include <cmath>

#define N      50000
#define E      800000
#define NFEAT  128
#define NHID   128
#define NCLASS 40
#define NUM_HOPS 4
#define NF     (N * NHID)   // 6,400,000 elements per h buffer
#define NBKT   196          // scatter buckets: 256 rows each
#define BCAP   5888         // slots per bucket (mean 4096+pads<=768, +16 sigma margin)
#define XSTR   132          // LDS row stride in attn kernel (conflict break)
#define HSTR   136          // LDS row stride (shorts) in k_hop: 272B = 256B row + 16B pad
#define HROWS  8            // rows per k_hop block (row split across quarter pair; grid 6250)
#define SC1_EPT 16          // edges per thread in k_scat1 (196 blocks; R2-verified best)
#define SC1_BLK ((E + 256 * SC1_EPT - 1) / (256 * SC1_EPT))

typedef __attribute__((ext_vector_type(8))) short bf16x8;   // 8 bf16 in 4 VGPRs
typedef __attribute__((ext_vector_type(4))) float f32x4;

// bf16 helpers (RTNE)
__device__ __forceinline__ unsigned bf16pack(float a, float b) {
    unsigned ua = __float_as_uint(a), ub = __float_as_uint(b);
    ua = (ua + 0x7fffu + ((ua >> 16) & 1u)) >> 16;
    ub = (ub + 0x7fffu + ((ub >> 16) & 1u)) >> 16;
    return ua | (ub << 16);
}
__device__ __forceinline__ unsigned short bf16s(float x) {
    unsigned u = __float_as_uint(x);
    u = (u + 0x7fffu + ((u >> 16) & 1u)) >> 16;
    return (unsigned short)u;
}
__device__ __forceinline__ float bf16lo(unsigned u) { return __uint_as_float(u << 16); }
__device__ __forceinline__ float bf16hi(unsigned u) { return __uint_as_float(u & 0xffff0000u); }

// ---------------- CSR build: fixed bucket regions, no global hist/scan ----------------

__global__ void k_binit2(int* __restrict__ bcur) {
    int t = threadIdx.x;
    if (t < NBKT) bcur[t] = t * BCAP;
}

// Pass 1: block-level multi-split into 196 row-buckets (u64: row&255 hi, col|bf16val lo)
__global__ __launch_bounds__(256) void k_scat1(const int* __restrict__ row,
                                               const int* __restrict__ col,
                                               const float* __restrict__ val,
                                               int* __restrict__ bcur,
                                               unsigned long long* __restrict__ evt) {
    __shared__ int lhist[NBKT];
    __shared__ int gbase[NBKT];
    __shared__ int lcur[NBKT];
    int t = threadIdx.x;
    int e0 = blockIdx.x * (256 * SC1_EPT);
    for (int i = t; i < NBKT; i += 256) { lhist[i] = 0; lcur[i] = 0; }
    __syncthreads();
    // phase A: per-bucket count (rows cached in registers)
    int rows[SC1_EPT];
#pragma unroll
    for (int i = 0; i < SC1_EPT; ++i) {
        int e = e0 + i * 256 + t;
        int r = (e < E) ? row[e] : -1;
        rows[i] = r;
        if (r >= 0) atomicAdd(&lhist[r >> 8], 1);
    }
    __syncthreads();
    // reserve one contiguous chunk per non-empty bucket
    for (int i = t; i < NBKT; i += 256) {
        int c = lhist[i];
        gbase[i] = c ? atomicAdd(&bcur[i], c) : 0;
    }
    __syncthreads();
    // phase B: chunked writes (guarded against impossible bucket overflow)
#pragma unroll
    for (int i = 0; i < SC1_EPT; ++i) {
        int r = rows[i];
        if (r >= 0) {
            int e = e0 + i * 256 + t;
            int b = r >> 8;
            int off = atomicAdd(&lcur[b], 1);
            size_t idx = (size_t)gbase[b] + off;
            if (idx < (size_t)(b + 1) * BCAP) {
                unsigned v = __float_as_uint(val[e]);
                v = (v + 0x7fffu + ((v >> 16) & 1u)) & 0xffff0000u;
                evt[idx] = ((unsigned long long)(r & 255) << 32)
                         | ((unsigned)col[e] | v);
            }
        }
    }
}

// Pass 2: per-bucket: count rows, block-scan (x4-padded), emit rpb/rpe, scatter, pad-fill.
__global__ __launch_bounds__(256) void k_scat2b(const int* __restrict__ bcur,
                                                const unsigned long long* __restrict__ evt,
                                                unsigned* __restrict__ ev,
                                                int* __restrict__ rpb,
                                                int* __restrict__ rpe) {
    __shared__ int lhist[256];
    __shared__ int ws[4];
    __shared__ int cur[256];
    int b = blockIdx.x;
    int t = threadIdx.x;
    int base = b * BCAP;
    int ecnt = bcur[b] - base;
    if (ecnt > BCAP) ecnt = BCAP;
    lhist[t] = 0;
    __syncthreads();
    // count per local row
    for (int i = t; i < ecnt; i += 256)
        atomicAdd(&lhist[(int)(evt[(size_t)base + i] >> 32)], 1);
    __syncthreads();
    int cntr = lhist[t];
    int pc = (cntr + 3) & ~3;          // pad to x4
    // block scan of pc over 256 threads
    int lane = t & 63, wv_ = t >> 6;
    int incl = pc;
    for (int off = 1; off < 64; off <<= 1) {
        int u = __shfl_up(incl, off);
        if (lane >= off) incl += u;
    }
    if (lane == 63) ws[wv_] = incl;
    __syncthreads();
    int woff = 0;
    for (int k = 0; k < wv_; ++k) woff += ws[k];
    int rowbeg = base + (incl - pc + woff);
    int rt = b * 256 + t;
    if (rt < N) { rpb[rt] = rowbeg; rpe[rt] = rowbeg + pc; }
    cur[t] = rowbeg;
    __syncthreads();
    // scatter within bucket
    for (int i = t; i < ecnt; i += 256) {
        unsigned long long e = evt[(size_t)base + i];
        int r8 = (int)(e >> 32);
        int p = atomicAdd(&cur[r8], 1);
        ev[p] = (unsigned)e;
    }
    __syncthreads();
    // pad-fill (<=3 per row; cur[t] is rowbeg+cntr)
    int e1 = rowbeg + pc;
    for (int p = cur[t]; p < e1; ++p) ev[p] = 0;
}

// ---------------- fused: feature score + f32->bf16 convert (one pass over features) ----

__global__ void k_cvtf(const float* __restrict__ f, const float* __restrict__ att_w,
                       float* __restrict__ fs, unsigned short* __restrict__ fb) {
    int node = (blockIdx.x * blockDim.x + threadIdx.x) >> 6;
    if (node >= N) return;
    int lane = threadIdx.x & 63;
    const float2 wf = ((const float2*)(att_w + NHID))[lane];
    const float2 fv = ((const float2*)(f + (size_t)node * NFEAT))[lane];
    ((unsigned*)(fb + (size_t)node * NFEAT))[lane] = bf16pack(fv.x, fv.y);
    float s = fv.x * wf.x + fv.y * wf.y;
    for (int off = 32; off; off >>= 1) s += __shfl_xor(s, off);
    if (lane == 0) fs[node] = s;
}

// W (4 x 128 x 128, [hop][k][n]) -> transposed bf16 Wbt [hop][n][k]
__global__ void k_cvt_w(const float* __restrict__ Wg, unsigned short* __restrict__ Wbt) {
    int idx = blockIdx.x * blockDim.x + threadIdx.x;
    if (idx >= NUM_HOPS * NHID * NHID) return;
    int i = idx >> 14;            // hop
    int rem = idx & 16383;
    int n = rem >> 7;             // out row (col of W)
    int k = rem & 127;            // out col (row of W)
    Wbt[idx] = bf16s(Wg[(i << 14) + k * NHID + n]);
}

// ---------------- Fused hop: SpMM (into LDS) + MFMA GEMM + relu + hop score ----------------
// Block = 256 threads = 4 waves = 8 rows; grid 6250 (~98 waves/CU demanded).
// Stage 1 (SpMM): each ROW is split across a QUARTER PAIR of one wave (halves of its
//   edge list, both x4); partial sums combined via __shfl_xor(a,16) (quarter q <-> q^1).
//   Halves the per-row dependent {ev -> gather -> ACC} chain (deg-16 row: ONE 8-edge
//   iteration per half) and doubles gathers in flight, with the R7-proven 8-edge body.
// Stage 2 (GEMM): 8-row tile padded into 16x16 MFMA (A rows 8..15 duplicate 0..7;
//   stores/score guarded to rows 0..7). Wave w -> n-quarter w: 2 n-tiles x 4 k = 8 MFMA.
//   C/D: col=lane&15, row=quad*4+reg (verified mapping).

__global__ __launch_bounds__(256) void k_hop(const int* __restrict__ rpb,
                                             const int* __restrict__ rpe,
                                             const unsigned* __restrict__ ev,
                                             const unsigned short* __restrict__ xb,
                                             const unsigned short* __restrict__ Wbt,
                                             const float* __restrict__ att_w,
                                             unsigned short* __restrict__ yb,
                                             float* __restrict__ Sh) {
    __shared__ unsigned short xsm[HROWS * HSTR];
    __shared__ float sS[HROWS][4];
    int t = threadIdx.x;
    int w = t >> 6;           // wave 0..3
    int lane = t & 63;
    int quad = lane >> 4;
    int l15 = lane & 15;
    int rowb = blockIdx.x * HROWS;
    const uint4* xq = (const uint4*)xb;        // row r -> base index r*16

    // ---- stage 1: SpMM; row rl = w*2 + (quad>>1), half = quad&1 ----
#define ACC8(g, v)                                                            \
    do {                                                                      \
        a0 = fmaf((v), bf16lo((g).x), a0); a1 = fmaf((v), bf16hi((g).x), a1); \
        a2 = fmaf((v), bf16lo((g).y), a2); a3 = fmaf((v), bf16hi((g).y), a3); \
        a4 = fmaf((v), bf16lo((g).z), a4); a5 = fmaf((v), bf16hi((g).z), a5); \
        a6 = fmaf((v), bf16lo((g).w), a6); a7 = fmaf((v), bf16hi((g).w), a7); \
    } while (0)
    {
        int rl  = w * 2 + (quad >> 1);         // local row 0..7
        int h   = quad & 1;                    // half of the edge list
        int gl  = rowb + rl;
        float a0 = 0.f, a1 = 0.f, a2 = 0.f, a3 = 0.f;
        float a4 = 0.f, a5 = 0.f, a6 = 0.f, a7 = 0.f;
        if (gl < N) {
            int beg = rpb[gl], end = rpe[gl];  // padded count, multiple of 4
            int pc  = end - beg;
            int h0  = ((pc >> 1) + 3) & ~3;    // first-half size (x4, <= pc)
            if (h0 > pc) h0 = pc;
            int jb = h ? (beg + h0) : beg;
            int je = h ? end : (beg + h0);
            int j = jb;
            for (; j + 8 <= je; j += 8) {
                uint4 p0 = *(const uint4*)(ev + j);
                uint4 p1 = *(const uint4*)(ev + j + 4);
                uint4 g0 = xq[(size_t)(p0.x & 0xffffu) * 16 + l15];
                uint4 g1 = xq[(size_t)(p0.y & 0xffffu) * 16 + l15];
                uint4 g2 = xq[(size_t)(p0.z & 0xffffu) * 16 + l15];
                uint4 g3 = xq[(size_t)(p0.w & 0xffffu) * 16 + l15];
                uint4 g4 = xq[(size_t)(p1.x & 0xffffu) * 16 + l15];
                uint4 g5 = xq[(size_t)(p1.y & 0xffffu) * 16 + l15];
                uint4 g6 = xq[(size_t)(p1.z & 0xffffu) * 16 + l15];
                uint4 g7 = xq[(size_t)(p1.w & 0xffffu) * 16 + l15];
                ACC8(g0, bf16hi(p0.x));
                ACC8(g1, bf16hi(p0.y));
                ACC8(g2, bf16hi(p0.z));
                ACC8(g3, bf16hi(p0.w));
                ACC8(g4, bf16hi(p1.x));
                ACC8(g5, bf16hi(p1.y));
                ACC8(g6, bf16hi(p1.z));
                ACC8(g7, bf16hi(p1.w));
            }
            if (j < je) {   // exactly 4 remain
                uint4 p0 = *(const uint4*)(ev + j);
                uint4 g0 = xq[(size_t)(p0.x & 0xffffu) * 16 + l15];
                uint4 g1 = xq[(size_t)(p0.y & 0xffffu) * 16 + l15];
                uint4 g2 = xq[(size_t)(p0.z & 0xffffu) * 16 + l15];
                uint4 g3 = xq[(size_t)(p0.w & 0xffffu) * 16 + l15];
                ACC8(g0, bf16hi(p0.x));
                ACC8(g1, bf16hi(p0.y));
                ACC8(g2, bf16hi(p0.z));
                ACC8(g3, bf16hi(p0.w));
            }
        }
        // combine the two halves (quarter q <-> q^1, same l15)
        a0 += __shfl_xor(a0, 16);
        a1 += __shfl_xor(a1, 16);
        a2 += __shfl_xor(a2, 16);
        a3 += __shfl_xor(a3, 16);
        a4 += __shfl_xor(a4, 16);
        a5 += __shfl_xor(a5, 16);
        a6 += __shfl_xor(a6, 16);
        a7 += __shfl_xor(a7, 16);
        if (h == 0) {
            uint4 o;
            o.x = bf16pack(a0, a1);
            o.y = bf16pack(a2, a3);
            o.z = bf16pack(a4, a5);
            o.w = bf16pack(a6, a7);
            *(uint4*)(xsm + (size_t)rl * HSTR + l15 * 8) = o;
        }
    }
#undef ACC8
    __syncthreads();

    // ---- stage 2: GEMM from LDS A-frags; 8-row tile padded to 16 (rows 8..15 dup) ----
    bf16x8 af[4];
#pragma unroll
    for (int s = 0; s < 4; ++s) {
        uint4 ua = *(const uint4*)(xsm + (size_t)(l15 & 7) * HSTR + s * 32 + quad * 8);
        af[s] = __builtin_bit_cast(bf16x8, ua);
    }

    f32x4 acc[2];
#pragma unroll
    for (int nt = 0; nt < 2; ++nt) acc[nt] = (f32x4){0.f, 0.f, 0.f, 0.f};

#pragma unroll
    for (int nt = 0; nt < 2; ++nt) {
        int ntg = w * 2 + nt;
#pragma unroll
        for (int s = 0; s < 4; ++s) {
            uint4 ub = *(const uint4*)(Wbt + ((size_t)(ntg * 16 + l15) * NHID + s * 32 + quad * 8));
            bf16x8 bfv = __builtin_bit_cast(bf16x8, ub);
            acc[nt] = __builtin_amdgcn_mfma_f32_16x16x32_bf16(af[s], bfv, acc[nt], 0, 0, 0);
        }
    }

    // per-lane w_h values for the 2 cols this lane owns in its quarter
    float whl[2];
#pragma unroll
    for (int nt = 0; nt < 2; ++nt) whl[nt] = att_w[(w * 2 + nt) * 16 + l15];

    float scr[4] = {0.f, 0.f, 0.f, 0.f};
#pragma unroll
    for (int nt = 0; nt < 2; ++nt) {
#pragma unroll
        for (int r = 0; r < 4; ++r) {
            float v = fmaxf(acc[nt][r], 0.f);
            scr[r] = fmaf(v, whl[nt], scr[r]);
            int row16 = quad * 4 + r;          // D row 0..15; valid rows 0..7
            int grow = rowb + row16;
            if (row16 < HROWS && grow < N)
                yb[(size_t)grow * NHID + (w * 2 + nt) * 16 + l15] = bf16s(v);
        }
    }
    // score reduction across the 16 col-lanes (stays within quad); rows 0..7 only
#pragma unroll
    for (int r = 0; r < 4; ++r) {
        float p = scr[r];
        p += __shfl_xor(p, 1);
        p += __shfl_xor(p, 2);
        p += __shfl_xor(p, 4);
        p += __shfl_xor(p, 8);
        int row16 = quad * 4 + r;
        if (l15 == 0 && row16 < HROWS) sS[row16][w] = p;
    }
    __syncthreads();
    if (t < HROWS) {
        int grow = rowb + t;
        if (grow < N) Sh[grow] = sS[t][0] + sS[t][1] + sS[t][2] + sS[t][3];
    }
}

// ---------------- Attention + output head (64 nodes/block, bf16 h input) ----------------

__global__ __launch_bounds__(256) void k_attn_final(const unsigned short* __restrict__ hb,
                                                    const float* __restrict__ S,
                                                    const float* __restrict__ fs,
                                                    const float* __restrict__ att_b,
                                                    const float* __restrict__ fc_w,
                                                    const float* __restrict__ fc_b,
                                                    float* __restrict__ out) {
    __shared__ float xs[64 * XSTR];
    __shared__ float wv[4][64];
    int t = threadIdx.x;
    int base = blockIdx.x * 64;

    if (t < 64) {
        int node = base + t;
        if (node < N) {
            float b = att_b[0] + fs[node];
            float g0 = 1.f / (1.f + __expf(-(S[0 * N + node] + b)));
            float g1 = 1.f / (1.f + __expf(-(S[1 * N + node] + b)));
            float g2 = 1.f / (1.f + __expf(-(S[2 * N + node] + b)));
            float g3 = 1.f / (1.f + __expf(-(S[3 * N + node] + b)));
            float m = fmaxf(fmaxf(g0, g1), fmaxf(g2, g3));
            float e0 = __expf(g0 - m), e1 = __expf(g1 - m);
            float e2 = __expf(g2 - m), e3 = __expf(g3 - m);
            float inv = 1.f / (e0 + e1 + e2 + e3);
            wv[0][t] = e0 * inv; wv[1][t] = e1 * inv;
            wv[2][t] = e2 * inv; wv[3][t] = e3 * inv;
        } else {
            wv[0][t] = 0.f; wv[1][t] = 0.f; wv[2][t] = 0.f; wv[3][t] = 0.f;
        }
    }
    __syncthreads();

#pragma unroll
    for (int qq = 0; qq < 4; ++qq) {
        int idx = qq * 256 + t;     // 0..1023
        int nl = idx >> 4;          // local node 0..63
        int d8 = idx & 15;          // uint4 (8-elem) index within row
        int node = base + nl;
        float o[8] = {0.f, 0.f, 0.f, 0.f, 0.f, 0.f, 0.f, 0.f};
        if (node < N) {
            float w0 = wv[0][nl], w1 = wv[1][nl], w2 = wv[2][nl], w3 = wv[3][nl];
            uint4 u0 = ((const uint4*)(hb + 0 * (size_t)NF + (size_t)node * NHID))[d8];
            uint4 u1 = ((const uint4*)(hb + 1 * (size_t)NF + (size_t)node * NHID))[d8];
            uint4 u2 = ((const uint4*)(hb + 2 * (size_t)NF + (size_t)node * NHID))[d8];
            uint4 u3 = ((const uint4*)(hb + 3 * (size_t)NF + (size_t)node * NHID))[d8];
            o[0] = w0 * bf16lo(u0.x) + w1 * bf16lo(u1.x) + w2 * bf16lo(u2.x) + w3 * bf16lo(u3.x);
            o[1] = w0 * bf16hi(u0.x) + w1 * bf16hi(u1.x) + w2 * bf16hi(u2.x) + w3 * bf16hi(u3.x);
            o[2] = w0 * bf16lo(u0.y) + w1 * bf16lo(u1.y) + w2 * bf16lo(u2.y) + w3 * bf16lo(u3.y);
            o[3] = w0 * bf16hi(u0.y) + w1 * bf16hi(u1.y) + w2 * bf16hi(u2.y) + w3 * bf16hi(u3.y);
            o[4] = w0 * bf16lo(u0.z) + w1 * bf16lo(u1.z) + w2 * bf16lo(u2.z) + w3 * bf16lo(u3.z);
            o[5] = w0 * bf16hi(u0.z) + w1 * bf16hi(u1.z) + w2 * bf16hi(u2.z) + w3 * bf16hi(u3.z);
            o[6] = w0 * bf16lo(u0.w) + w1 * bf16lo(u1.w) + w2 * bf16lo(u2.w) + w3 * bf16lo(u3.w);
            o[7] = w0 * bf16hi(u0.w) + w1 * bf16hi(u1.w) + w2 * bf16hi(u2.w) + w3 * bf16hi(u3.w);
        }
        float* xp = &xs[nl * XSTR + (d8 << 3)];
        *(float4*)xp       = make_float4(o[0], o[1], o[2], o[3]);
        *(float4*)(xp + 4) = make_float4(o[4], o[5], o[6], o[7]);
    }
    __syncthreads();

    int cq = t & 15;                     // col quad (active: cq<10)
    int rg = t >> 4;                     // row group: rows rg*4 .. rg*4+3
    int cb = (cq < 10) ? (cq << 2) : 36; // clamped col base: loads stay in-bounds
    float4 bias = *(const float4*)(fc_b + cb);
    float4 acc[4];
#pragma unroll
    for (int r = 0; r < 4; ++r) acc[r] = bias;
    for (int k4 = 0; k4 < NHID / 4; ++k4) {
        float4 w0 = *(const float4*)(fc_w + (size_t)(4 * k4 + 0) * NCLASS + cb);
        float4 w1 = *(const float4*)(fc_w + (size_t)(4 * k4 + 1) * NCLASS + cb);
        float4 w2 = *(const float4*)(fc_w + (size_t)(4 * k4 + 2) * NCLASS + cb);
        float4 w3 = *(const float4*)(fc_w + (size_t)(4 * k4 + 3) * NCLASS + cb);
#pragma unroll
        for (int r = 0; r < 4; ++r) {
            float4 xv = *(const float4*)&xs[(rg * 4 + r) * XSTR + (k4 << 2)];
            acc[r].x = fmaf(xv.x, w0.x, acc[r].x);
            acc[r].y = fmaf(xv.x, w0.y, acc[r].y);
            acc[r].z = fmaf(xv.x, w0.z, acc[r].z);
            acc[r].w = fmaf(xv.x, w0.w, acc[r].w);
            acc[r].x = fmaf(xv.y, w1.x, acc[r].x);
            acc[r].y = fmaf(xv.y, w1.y, acc[r].y);
            acc[r].z = fmaf(xv.y, w1.z, acc[r].z);
            acc[r].w = fmaf(xv.y, w1.w, acc[r].w);
            acc[r].x = fmaf(xv.z, w2.x, acc[r].x);
            acc[r].y = fmaf(xv.z, w2.y, acc[r].y);
            acc[r].z = fmaf(xv.z, w2.z, acc[r].z);
            acc[r].w = fmaf(xv.z, w2.w, acc[r].w);
            acc[r].x = fmaf(xv.w, w3.x, acc[r].x);
            acc[r].y = fmaf(xv.w, w3.y, acc[r].y);
            acc[r].z = fmaf(xv.w, w3.z, acc[r].z);
            acc[r].w = fmaf(xv.w, w3.w, acc[r].w);
        }
    }
#pragma unroll
    for (int r = 0; r < 4; ++r) {
        int nd = base + rg * 4 + r;
        float mloc = (cq < 10)
            ? fmaxf(fmaxf(acc[r].x, acc[r].y), fmaxf(acc[r].z, acc[r].w))
            : -INFINITY;
        float m = mloc;
        m = fmaxf(m, __shfl_xor(m, 1));
        m = fmaxf(m, __shfl_xor(m, 2));
        m = fmaxf(m, __shfl_xor(m, 4));
        m = fmaxf(m, __shfl_xor(m, 8));
        float sloc = (cq < 10)
            ? (__expf(acc[r].x - m) + __expf(acc[r].y - m) +
               __expf(acc[r].z - m) + __expf(acc[r].w - m))
            : 0.f;
        float s = sloc;
        s += __shfl_xor(s, 1);
        s += __shfl_xor(s, 2);
        s += __shfl_xor(s, 4);
        s += __shfl_xor(s, 8);
        float ls = m + logf(s);
        if (cq < 10 && nd < N) {
            float4 o;
            o.x = acc[r].x - ls;
            o.y = acc[r].y - ls;
            o.z = acc[r].z - ls;
            o.w = acc[r].w - ls;
            *(float4*)(out + (size_t)nd * NCLASS + cb) = o;
        }
    }
}

// ---------------- launch ----------------

extern "C" void kernel_launch(void* const* d_in, const int* in_sizes, int n_in,
                              void* d_out, int out_size, void* d_ws, size_t ws_size,
                              hipStream_t stream) {
    const float* features = (const float*)d_in[0];
    const int*   erow     = (const int*)d_in[1];
    const int*   ecol     = (const int*)d_in[2];
    const float* eval_    = (const float*)d_in[3];
    const float* Wg       = (const float*)d_in[4];
    const float* att_w    = (const float*)d_in[5];
    const float* att_b    = (const float*)d_in[6];
    const float* fc_w     = (const float*)d_in[7];
    const float* fc_b     = (const float*)d_in[8];
    float*       out      = (float*)d_out;

    // workspace layout (4-byte slots; ~70 MB)
    const size_t SLOTS = 2 * (size_t)NF        // hbb: 4 x NF bf16 (aliased as evt during CSR build)
                       + (size_t)NF / 2        // fb: NF bf16
                       + 32768                 // Wbt: 4*128*128 bf16
                       + (size_t)NBKT * BCAP   // ev (packed u32, bucket regions)
                       + 3 * (size_t)N         // rpb, rpe, fs
                       + NBKT                  // bcur
                       + 4 * (size_t)N;        // S
    if (ws_size < SLOTS * 4) return;  // readable failure instead of OOB crash

    unsigned short* hbb  = (unsigned short*)d_ws;                // 4*NF bf16
    unsigned short* fb   = hbb + 4 * (size_t)NF;                 // NF bf16
    unsigned short* Wbt  = fb + (size_t)NF;                      // 65536 bf16
    unsigned*       ev   = (unsigned*)(Wbt + 65536);             // NBKT*BCAP u32
    int*            rpb  = (int*)(ev + (size_t)NBKT * BCAP);     // N
    int*            rpe  = rpb + N;                              // N
    float*          fs   = (float*)(rpe + N);                    // N
    int*            bcur = (int*)(fs + N);                       // NBKT
    float*          S    = (float*)(bcur + NBKT);                // 4*N hop scores
    // temp binned-edge buffer (u64), only live during CSR build -> alias hbb
    unsigned long long* evt = (unsigned long long*)hbb;

    // CSR build: bucket regions, single-scan (no global hist/scan, no memsets)
    k_binit2<<<1, 256, 0, stream>>>(bcur);
    k_scat1<<<SC1_BLK, 256, 0, stream>>>(erow, ecol, eval_, bcur, evt);
    k_scat2b<<<NBKT, 256, 0, stream>>>(bcur, evt, ev, rpb, rpe);

    // fused feature score + bf16 feature copy; transposed bf16 weights
    k_cvtf<<<(N * 64 + 255) / 256, 256, 0, stream>>>(features, att_w, fs, fb);
    k_cvt_w<<<(NUM_HOPS * NHID * NHID + 255) / 256, 256, 0, stream>>>(Wg, Wbt);

    // hops: fused spmm (bf16, f32 acc, LDS, split-row) + MFMA gemm per hop (8 rows/block)
    const unsigned short* xb = fb;
    for (int i = 0; i < NUM_HOPS; ++i) {
        k_hop<<<(N + HROWS - 1) / HROWS, 256, 0, stream>>>(rpb, rpe, ev, xb,
                                                 Wbt + (size_t)i * NHID * NHID,
                                                 att_w, hbb + (size_t)i * NF,
                                                 S + (size_t)i * N);
        xb = hbb + (size_t)i * NF;
    }

    // attention + fc + log_softmax (bf16 h input, f32 math)
    k_attn_final<<<(N + 63) / 64, 256, 0, stream>>>(hbb, S, fs, att_b, fc_w, fc_b, out);
}

// Round 13
// 306.573 us; speedup vs baseline: 1.1053x; 1.1053x over previous
//
#include <hip/hip_runtime.h>
#include <cmath>

#define N      50000
#define E      800000
#define NFEAT  128
#define NHID   128
#define NCLASS 40
#define NUM_HOPS 4
#define NF     (N * NHID)   // 6,400,000 elements per h buffer
#define NBKT   196          // scatter buckets: 256 rows each
#define BCAP   5888         // slots per bucket (mean 4096+pads<=768, +16 sigma margin)
#define XSTR   132          // LDS row stride in attn kernel (conflict break)
#define HSTR   136          // LDS row stride (shorts) in k_hop: 272B = 256B row + 16B pad
#define HROWS  16           // rows per k_hop block (256 threads; grid 3125) -- R9-proven
#define SC1_EPT 8           // edges per thread in k_scat1 (391 blocks, ~6 waves/CU)
#define SC1_BLK ((E + 256 * SC1_EPT - 1) / (256 * SC1_EPT))

typedef __attribute__((ext_vector_type(8))) short bf16x8;   // 8 bf16 in 4 VGPRs
typedef __attribute__((ext_vector_type(4))) float f32x4;

// bf16 helpers (RTNE)
__device__ __forceinline__ unsigned bf16pack(float a, float b) {
    unsigned ua = __float_as_uint(a), ub = __float_as_uint(b);
    ua = (ua + 0x7fffu + ((ua >> 16) & 1u)) >> 16;
    ub = (ub + 0x7fffu + ((ub >> 16) & 1u)) >> 16;
    return ua | (ub << 16);
}
__device__ __forceinline__ unsigned short bf16s(float x) {
    unsigned u = __float_as_uint(x);
    u = (u + 0x7fffu + ((u >> 16) & 1u)) >> 16;
    return (unsigned short)u;
}
__device__ __forceinline__ float bf16lo(unsigned u) { return __uint_as_float(u << 16); }
__device__ __forceinline__ float bf16hi(unsigned u) { return __uint_as_float(u & 0xffff0000u); }

// ---------------- CSR build: fixed bucket regions, no global hist/scan ----------------

__global__ void k_binit2(int* __restrict__ bcur) {
    int t = threadIdx.x;
    if (t < NBKT) bcur[t] = t * BCAP;
}

// Pass 1: block-level multi-split into 196 row-buckets (u64: row&255 hi, col|bf16val lo)
__global__ __launch_bounds__(256) void k_scat1(const int* __restrict__ row,
                                               const int* __restrict__ col,
                                               const float* __restrict__ val,
                                               int* __restrict__ bcur,
                                               unsigned long long* __restrict__ evt) {
    __shared__ int lhist[NBKT];
    __shared__ int gbase[NBKT];
    __shared__ int lcur[NBKT];
    int t = threadIdx.x;
    int e0 = blockIdx.x * (256 * SC1_EPT);
    for (int i = t; i < NBKT; i += 256) { lhist[i] = 0; lcur[i] = 0; }
    __syncthreads();
    // phase A: per-bucket count (rows cached in registers)
    int rows[SC1_EPT];
#pragma unroll
    for (int i = 0; i < SC1_EPT; ++i) {
        int e = e0 + i * 256 + t;
        int r = (e < E) ? row[e] : -1;
        rows[i] = r;
        if (r >= 0) atomicAdd(&lhist[r >> 8], 1);
    }
    __syncthreads();
    // reserve one contiguous chunk per non-empty bucket
    for (int i = t; i < NBKT; i += 256) {
        int c = lhist[i];
        gbase[i] = c ? atomicAdd(&bcur[i], c) : 0;
    }
    __syncthreads();
    // phase B: chunked writes (guarded against impossible bucket overflow)
#pragma unroll
    for (int i = 0; i < SC1_EPT; ++i) {
        int r = rows[i];
        if (r >= 0) {
            int e = e0 + i * 256 + t;
            int b = r >> 8;
            int off = atomicAdd(&lcur[b], 1);
            size_t idx = (size_t)gbase[b] + off;
            if (idx < (size_t)(b + 1) * BCAP) {
                unsigned v = __float_as_uint(val[e]);
                v = (v + 0x7fffu + ((v >> 16) & 1u)) & 0xffff0000u;
                evt[idx] = ((unsigned long long)(r & 255) << 32)
                         | ((unsigned)col[e] | v);
            }
        }
    }
}

// Pass 2: per-bucket: count rows, block-scan (x4-padded), emit rpb/rpe, scatter, pad-fill.
__global__ __launch_bounds__(256) void k_scat2b(const int* __restrict__ bcur,
                                                const unsigned long long* __restrict__ evt,
                                                unsigned* __restrict__ ev,
                                                int* __restrict__ rpb,
                                                int* __restrict__ rpe) {
    __shared__ int lhist[256];
    __shared__ int ws[4];
    __shared__ int cur[256];
    int b = blockIdx.x;
    int t = threadIdx.x;
    int base = b * BCAP;
    int ecnt = bcur[b] - base;
    if (ecnt > BCAP) ecnt = BCAP;
    lhist[t] = 0;
    __syncthreads();
    // count per local row
    for (int i = t; i < ecnt; i += 256)
        atomicAdd(&lhist[(int)(evt[(size_t)base + i] >> 32)], 1);
    __syncthreads();
    int cntr = lhist[t];
    int pc = (cntr + 3) & ~3;          // pad to x4
    // block scan of pc over 256 threads
    int lane = t & 63, wv_ = t >> 6;
    int incl = pc;
    for (int off = 1; off < 64; off <<= 1) {
        int u = __shfl_up(incl, off);
        if (lane >= off) incl += u;
    }
    if (lane == 63) ws[wv_] = incl;
    __syncthreads();
    int woff = 0;
    for (int k = 0; k < wv_; ++k) woff += ws[k];
    int rowbeg = base + (incl - pc + woff);
    int rt = b * 256 + t;
    if (rt < N) { rpb[rt] = rowbeg; rpe[rt] = rowbeg + pc; }
    cur[t] = rowbeg;
    __syncthreads();
    // scatter within bucket
    for (int i = t; i < ecnt; i += 256) {
        unsigned long long e = evt[(size_t)base + i];
        int r8 = (int)(e >> 32);
        int p = atomicAdd(&cur[r8], 1);
        ev[p] = (unsigned)e;
    }
    __syncthreads();
    // pad-fill (<=3 per row; cur[t] is rowbeg+cntr)
    int e1 = rowbeg + pc;
    for (int p = cur[t]; p < e1; ++p) ev[p] = 0;
}

// ---------------- fused: feature score + f32->bf16 convert (one pass over features) ----

__global__ void k_cvtf(const float* __restrict__ f, const float* __restrict__ att_w,
                       float* __restrict__ fs, unsigned short* __restrict__ fb) {
    int node = (blockIdx.x * blockDim.x + threadIdx.x) >> 6;
    if (node >= N) return;
    int lane = threadIdx.x & 63;
    const float2 wf = ((const float2*)(att_w + NHID))[lane];
    const float2 fv = ((const float2*)(f + (size_t)node * NFEAT))[lane];
    ((unsigned*)(fb + (size_t)node * NFEAT))[lane] = bf16pack(fv.x, fv.y);
    float s = fv.x * wf.x + fv.y * wf.y;
    for (int off = 32; off; off >>= 1) s += __shfl_xor(s, off);
    if (lane == 0) fs[node] = s;
}

// W (4 x 128 x 128, [hop][k][n]) -> transposed bf16 Wbt [hop][n][k]
__global__ void k_cvt_w(const float* __restrict__ Wg, unsigned short* __restrict__ Wbt) {
    int idx = blockIdx.x * blockDim.x + threadIdx.x;
    if (idx >= NUM_HOPS * NHID * NHID) return;
    int i = idx >> 14;            // hop
    int rem = idx & 16383;
    int n = rem >> 7;             // out row (col of W)
    int k = rem & 127;            // out col (row of W)
    Wbt[idx] = bf16s(Wg[(i << 14) + k * NHID + n]);
}

// ---------------- Fused hop: SpMM (into LDS) + MFMA GEMM + relu + hop score ----------------
// R9-proven structure (36us/hop floor). Block = 256 threads = 4 waves = 16 rows; grid 3125.
// Stage 1 (SpMM): 16 quarters x 1 row each; 16 lanes gather x rows (uint4 = 256B row),
//   f32 acc, pack bf16 -> xsm[16][HSTR]. 8-edge unroll (R7-proven; 16-wide regressed R8).
// Stage 2 (GEMM): wave w -> n-quarter w: 2 n-tiles x 4 k-steps = 8 MFMA; all waves read
//   the same 16-row A-frags. Per-row score quarters combined via sS[16][4].
//   C/D: col=lane&15, row=quad*4+reg (verified mapping).
// Post-R12 note: past ~30% occupancy this kernel is gather-subsystem-bound (R8 ILP null,
// R11 degree-sort null, R12 row-split regressed at 57% occupancy) -- do not re-attempt
// wave-level restructuring without new counter evidence.

__global__ __launch_bounds__(256) void k_hop(const int* __restrict__ rpb,
                                             const int* __restrict__ rpe,
                                             const unsigned* __restrict__ ev,
                                             const unsigned short* __restrict__ xb,
                                             const unsigned short* __restrict__ Wbt,
                                             const float* __restrict__ att_w,
                                             unsigned short* __restrict__ yb,
                                             float* __restrict__ Sh) {
    __shared__ unsigned short xsm[HROWS * HSTR];
    __shared__ float sS[HROWS][4];
    int t = threadIdx.x;
    int w = t >> 6;           // wave 0..3
    int lane = t & 63;
    int quad = lane >> 4;
    int l15 = lane & 15;
    int rowb = blockIdx.x * HROWS;
    const uint4* xq = (const uint4*)xb;        // row r -> base index r*16

    // ---- stage 1: SpMM for this block's 16 rows -> LDS (1 row per quarter) ----
#define ACC8(g, v)                                                            \
    do {                                                                      \
        a0 = fmaf((v), bf16lo((g).x), a0); a1 = fmaf((v), bf16hi((g).x), a1); \
        a2 = fmaf((v), bf16lo((g).y), a2); a3 = fmaf((v), bf16hi((g).y), a3); \
        a4 = fmaf((v), bf16lo((g).z), a4); a5 = fmaf((v), bf16hi((g).z), a5); \
        a6 = fmaf((v), bf16lo((g).w), a6); a7 = fmaf((v), bf16hi((g).w), a7); \
    } while (0)
    {
        int rl  = t >> 4;                      // local row 0..15
        int row = rowb + rl;
        float a0 = 0.f, a1 = 0.f, a2 = 0.f, a3 = 0.f;
        float a4 = 0.f, a5 = 0.f, a6 = 0.f, a7 = 0.f;
        if (row < N) {
            int beg = rpb[row], end = rpe[row];   // padded count, multiple of 4
            int j = beg;
            for (; j + 8 <= end; j += 8) {
                uint4 p0 = *(const uint4*)(ev + j);
                uint4 p1 = *(const uint4*)(ev + j + 4);
                uint4 g0 = xq[(size_t)(p0.x & 0xffffu) * 16 + l15];
                uint4 g1 = xq[(size_t)(p0.y & 0xffffu) * 16 + l15];
                uint4 g2 = xq[(size_t)(p0.z & 0xffffu) * 16 + l15];
                uint4 g3 = xq[(size_t)(p0.w & 0xffffu) * 16 + l15];
                uint4 g4 = xq[(size_t)(p1.x & 0xffffu) * 16 + l15];
                uint4 g5 = xq[(size_t)(p1.y & 0xffffu) * 16 + l15];
                uint4 g6 = xq[(size_t)(p1.z & 0xffffu) * 16 + l15];
                uint4 g7 = xq[(size_t)(p1.w & 0xffffu) * 16 + l15];
                ACC8(g0, bf16hi(p0.x));
                ACC8(g1, bf16hi(p0.y));
                ACC8(g2, bf16hi(p0.z));
                ACC8(g3, bf16hi(p0.w));
                ACC8(g4, bf16hi(p1.x));
                ACC8(g5, bf16hi(p1.y));
                ACC8(g6, bf16hi(p1.z));
                ACC8(g7, bf16hi(p1.w));
            }
            if (j < end) {   // exactly 4 remain
                uint4 p0 = *(const uint4*)(ev + j);
                uint4 g0 = xq[(size_t)(p0.x & 0xffffu) * 16 + l15];
                uint4 g1 = xq[(size_t)(p0.y & 0xffffu) * 16 + l15];
                uint4 g2 = xq[(size_t)(p0.z & 0xffffu) * 16 + l15];
                uint4 g3 = xq[(size_t)(p0.w & 0xffffu) * 16 + l15];
                ACC8(g0, bf16hi(p0.x));
                ACC8(g1, bf16hi(p0.y));
                ACC8(g2, bf16hi(p0.z));
                ACC8(g3, bf16hi(p0.w));
            }
        }
        uint4 o;
        o.x = bf16pack(a0, a1);
        o.y = bf16pack(a2, a3);
        o.z = bf16pack(a4, a5);
        o.w = bf16pack(a6, a7);
        *(uint4*)(xsm + (size_t)rl * HSTR + l15 * 8) = o;
    }
#undef ACC8
    __syncthreads();

    // ---- stage 2: GEMM from LDS A-frags; wave owns 16 rows x 32 cols (n-quarter w) ----
    bf16x8 af[4];
#pragma unroll
    for (int s = 0; s < 4; ++s) {
        uint4 ua = *(const uint4*)(xsm + (size_t)l15 * HSTR + s * 32 + quad * 8);
        af[s] = __builtin_bit_cast(bf16x8, ua);
    }

    f32x4 acc[2];
#pragma unroll
    for (int nt = 0; nt < 2; ++nt) acc[nt] = (f32x4){0.f, 0.f, 0.f, 0.f};

#pragma unroll
    for (int nt = 0; nt < 2; ++nt) {
        int ntg = w * 2 + nt;
#pragma unroll
        for (int s = 0; s < 4; ++s) {
            uint4 ub = *(const uint4*)(Wbt + ((size_t)(ntg * 16 + l15) * NHID + s * 32 + quad * 8));
            bf16x8 bfv = __builtin_bit_cast(bf16x8, ub);
            acc[nt] = __builtin_amdgcn_mfma_f32_16x16x32_bf16(af[s], bfv, acc[nt], 0, 0, 0);
        }
    }

    // per-lane w_h values for the 2 cols this lane owns in its quarter
    float whl[2];
#pragma unroll
    for (int nt = 0; nt < 2; ++nt) whl[nt] = att_w[(w * 2 + nt) * 16 + l15];

    float scr[4] = {0.f, 0.f, 0.f, 0.f};
#pragma unroll
    for (int nt = 0; nt < 2; ++nt) {
#pragma unroll
        for (int r = 0; r < 4; ++r) {
            float v = fmaxf(acc[nt][r], 0.f);
            scr[r] = fmaf(v, whl[nt], scr[r]);
            int grow = rowb + quad * 4 + r;
            if (grow < N)
                yb[(size_t)grow * NHID + (w * 2 + nt) * 16 + l15] = bf16s(v);
        }
    }
    // score quarter-reduction across the 16 col-lanes (stays within quad)
#pragma unroll
    for (int r = 0; r < 4; ++r) {
        float p = scr[r];
        p += __shfl_xor(p, 1);
        p += __shfl_xor(p, 2);
        p += __shfl_xor(p, 4);
        p += __shfl_xor(p, 8);
        if (l15 == 0) sS[quad * 4 + r][w] = p;
    }
    __syncthreads();
    if (t < HROWS) {
        int grow = rowb + t;
        if (grow < N) Sh[grow] = sS[t][0] + sS[t][1] + sS[t][2] + sS[t][3];
    }
}

// ---------------- Attention + output head (64 nodes/block, bf16 h input) ----------------

__global__ __launch_bounds__(256) void k_attn_final(const unsigned short* __restrict__ hb,
                                                    const float* __restrict__ S,
                                                    const float* __restrict__ fs,
                                                    const float* __restrict__ att_b,
                                                    const float* __restrict__ fc_w,
                                                    const float* __restrict__ fc_b,
                                                    float* __restrict__ out) {
    __shared__ float xs[64 * XSTR];
    __shared__ float wv[4][64];
    int t = threadIdx.x;
    int base = blockIdx.x * 64;

    if (t < 64) {
        int node = base + t;
        if (node < N) {
            float b = att_b[0] + fs[node];
            float g0 = 1.f / (1.f + __expf(-(S[0 * N + node] + b)));
            float g1 = 1.f / (1.f + __expf(-(S[1 * N + node] + b)));
            float g2 = 1.f / (1.f + __expf(-(S[2 * N + node] + b)));
            float g3 = 1.f / (1.f + __expf(-(S[3 * N + node] + b)));
            float m = fmaxf(fmaxf(g0, g1), fmaxf(g2, g3));
            float e0 = __expf(g0 - m), e1 = __expf(g1 - m);
            float e2 = __expf(g2 - m), e3 = __expf(g3 - m);
            float inv = 1.f / (e0 + e1 + e2 + e3);
            wv[0][t] = e0 * inv; wv[1][t] = e1 * inv;
            wv[2][t] = e2 * inv; wv[3][t] = e3 * inv;
        } else {
            wv[0][t] = 0.f; wv[1][t] = 0.f; wv[2][t] = 0.f; wv[3][t] = 0.f;
        }
    }
    __syncthreads();

#pragma unroll
    for (int qq = 0; qq < 4; ++qq) {
        int idx = qq * 256 + t;     // 0..1023
        int nl = idx >> 4;          // local node 0..63
        int d8 = idx & 15;          // uint4 (8-elem) index within row
        int node = base + nl;
        float o[8] = {0.f, 0.f, 0.f, 0.f, 0.f, 0.f, 0.f, 0.f};
        if (node < N) {
            float w0 = wv[0][nl], w1 = wv[1][nl], w2 = wv[2][nl], w3 = wv[3][nl];
            uint4 u0 = ((const uint4*)(hb + 0 * (size_t)NF + (size_t)node * NHID))[d8];
            uint4 u1 = ((const uint4*)(hb + 1 * (size_t)NF + (size_t)node * NHID))[d8];
            uint4 u2 = ((const uint4*)(hb + 2 * (size_t)NF + (size_t)node * NHID))[d8];
            uint4 u3 = ((const uint4*)(hb + 3 * (size_t)NF + (size_t)node * NHID))[d8];
            o[0] = w0 * bf16lo(u0.x) + w1 * bf16lo(u1.x) + w2 * bf16lo(u2.x) + w3 * bf16lo(u3.x);
            o[1] = w0 * bf16hi(u0.x) + w1 * bf16hi(u1.x) + w2 * bf16hi(u2.x) + w3 * bf16hi(u3.x);
            o[2] = w0 * bf16lo(u0.y) + w1 * bf16lo(u1.y) + w2 * bf16lo(u2.y) + w3 * bf16lo(u3.y);
            o[3] = w0 * bf16hi(u0.y) + w1 * bf16hi(u1.y) + w2 * bf16hi(u2.y) + w3 * bf16hi(u3.y);
            o[4] = w0 * bf16lo(u0.z) + w1 * bf16lo(u1.z) + w2 * bf16lo(u2.z) + w3 * bf16lo(u3.z);
            o[5] = w0 * bf16hi(u0.z) + w1 * bf16hi(u1.z) + w2 * bf16hi(u2.z) + w3 * bf16hi(u3.z);
            o[6] = w0 * bf16lo(u0.w) + w1 * bf16lo(u1.w) + w2 * bf16lo(u2.w) + w3 * bf16lo(u3.w);
            o[7] = w0 * bf16hi(u0.w) + w1 * bf16hi(u1.w) + w2 * bf16hi(u2.w) + w3 * bf16hi(u3.w);
        }
        float* xp = &xs[nl * XSTR + (d8 << 3)];
        *(float4*)xp       = make_float4(o[0], o[1], o[2], o[3]);
        *(float4*)(xp + 4) = make_float4(o[4], o[5], o[6], o[7]);
    }
    __syncthreads();

    int cq = t & 15;                     // col quad (active: cq<10)
    int rg = t >> 4;                     // row group: rows rg*4 .. rg*4+3
    int cb = (cq < 10) ? (cq << 2) : 36; // clamped col base: loads stay in-bounds
    float4 bias = *(const float4*)(fc_b + cb);
    float4 acc[4];
#pragma unroll
    for (int r = 0; r < 4; ++r) acc[r] = bias;
    for (int k4 = 0; k4 < NHID / 4; ++k4) {
        float4 w0 = *(const float4*)(fc_w + (size_t)(4 * k4 + 0) * NCLASS + cb);
        float4 w1 = *(const float4*)(fc_w + (size_t)(4 * k4 + 1) * NCLASS + cb);
        float4 w2 = *(const float4*)(fc_w + (size_t)(4 * k4 + 2) * NCLASS + cb);
        float4 w3 = *(const float4*)(fc_w + (size_t)(4 * k4 + 3) * NCLASS + cb);
#pragma unroll
        for (int r = 0; r < 4; ++r) {
            float4 xv = *(const float4*)&xs[(rg * 4 + r) * XSTR + (k4 << 2)];
            acc[r].x = fmaf(xv.x, w0.x, acc[r].x);
            acc[r].y = fmaf(xv.x, w0.y, acc[r].y);
            acc[r].z = fmaf(xv.x, w0.z, acc[r].z);
            acc[r].w = fmaf(xv.x, w0.w, acc[r].w);
            acc[r].x = fmaf(xv.y, w1.x, acc[r].x);
            acc[r].y = fmaf(xv.y, w1.y, acc[r].y);
            acc[r].z = fmaf(xv.y, w1.z, acc[r].z);
            acc[r].w = fmaf(xv.y, w1.w, acc[r].w);
            acc[r].x = fmaf(xv.z, w2.x, acc[r].x);
            acc[r].y = fmaf(xv.z, w2.y, acc[r].y);
            acc[r].z = fmaf(xv.z, w2.z, acc[r].z);
            acc[r].w = fmaf(xv.z, w2.w, acc[r].w);
            acc[r].x = fmaf(xv.w, w3.x, acc[r].x);
            acc[r].y = fmaf(xv.w, w3.y, acc[r].y);
            acc[r].z = fmaf(xv.w, w3.z, acc[r].z);
            acc[r].w = fmaf(xv.w, w3.w, acc[r].w);
        }
    }
#pragma unroll
    for (int r = 0; r < 4; ++r) {
        int nd = base + rg * 4 + r;
        float mloc = (cq < 10)
            ? fmaxf(fmaxf(acc[r].x, acc[r].y), fmaxf(acc[r].z, acc[r].w))
            : -INFINITY;
        float m = mloc;
        m = fmaxf(m, __shfl_xor(m, 1));
        m = fmaxf(m, __shfl_xor(m, 2));
        m = fmaxf(m, __shfl_xor(m, 4));
        m = fmaxf(m, __shfl_xor(m, 8));
        float sloc = (cq < 10)
            ? (__expf(acc[r].x - m) + __expf(acc[r].y - m) +
               __expf(acc[r].z - m) + __expf(acc[r].w - m))
            : 0.f;
        float s = sloc;
        s += __shfl_xor(s, 1);
        s += __shfl_xor(s, 2);
        s += __shfl_xor(s, 4);
        s += __shfl_xor(s, 8);
        float ls = m + logf(s);
        if (cq < 10 && nd < N) {
            float4 o;
            o.x = acc[r].x - ls;
            o.y = acc[r].y - ls;
            o.z = acc[r].z - ls;
            o.w = acc[r].w - ls;
            *(float4*)(out + (size_t)nd * NCLASS + cb) = o;
        }
    }
}

// ---------------- launch ----------------

extern "C" void kernel_launch(void* const* d_in, const int* in_sizes, int n_in,
                              void* d_out, int out_size, void* d_ws, size_t ws_size,
                              hipStream_t stream) {
    const float* features = (const float*)d_in[0];
    const int*   erow     = (const int*)d_in[1];
    const int*   ecol     = (const int*)d_in[2];
    const float* eval_    = (const float*)d_in[3];
    const float* Wg       = (const float*)d_in[4];
    const float* att_w    = (const float*)d_in[5];
    const float* att_b    = (const float*)d_in[6];
    const float* fc_w     = (const float*)d_in[7];
    const float* fc_b     = (const float*)d_in[8];
    float*       out      = (float*)d_out;

    // workspace layout (4-byte slots; ~70 MB)
    const size_t SLOTS = 2 * (size_t)NF        // hbb: 4 x NF bf16 (aliased as evt during CSR build)
                       + (size_t)NF / 2        // fb: NF bf16
                       + 32768                 // Wbt: 4*128*128 bf16
                       + (size_t)NBKT * BCAP   // ev (packed u32, bucket regions)
                       + 3 * (size_t)N         // rpb, rpe, fs
                       + NBKT                  // bcur
                       + 4 * (size_t)N;        // S
    if (ws_size < SLOTS * 4) return;  // readable failure instead of OOB crash

    unsigned short* hbb  = (unsigned short*)d_ws;                // 4*NF bf16
    unsigned short* fb   = hbb + 4 * (size_t)NF;                 // NF bf16
    unsigned short* Wbt  = fb + (size_t)NF;                      // 65536 bf16
    unsigned*       ev   = (unsigned*)(Wbt + 65536);             // NBKT*BCAP u32
    int*            rpb  = (int*)(ev + (size_t)NBKT * BCAP);     // N
    int*            rpe  = rpb + N;                              // N
    float*          fs   = (float*)(rpe + N);                    // N
    int*            bcur = (int*)(fs + N);                       // NBKT
    float*          S    = (float*)(bcur + NBKT);                // 4*N hop scores
    // temp binned-edge buffer (u64), only live during CSR build -> alias hbb
    unsigned long long* evt = (unsigned long long*)hbb;

    // CSR build: bucket regions, single-scan (no global hist/scan, no memsets)
    k_binit2<<<1, 256, 0, stream>>>(bcur);
    k_scat1<<<SC1_BLK, 256, 0, stream>>>(erow, ecol, eval_, bcur, evt);
    k_scat2b<<<NBKT, 256, 0, stream>>>(bcur, evt, ev, rpb, rpe);

    // fused feature score + bf16 feature copy; transposed bf16 weights
    k_cvtf<<<(N * 64 + 255) / 256, 256, 0, stream>>>(features, att_w, fs, fb);
    k_cvt_w<<<(NUM_HOPS * NHID * NHID + 255) / 256, 256, 0, stream>>>(Wg, Wbt);

    // hops: fused spmm (bf16, f32 acc, LDS) + MFMA gemm per hop (16 rows/block)
    const unsigned short* xb = fb;
    for (int i = 0; i < NUM_HOPS; ++i) {
        k_hop<<<(N + HROWS - 1) / HROWS, 256, 0, stream>>>(rpb, rpe, ev, xb,
                                                 Wbt + (size_t)i * NHID * NHID,
                                                 att_w, hbb + (size_t)i * NF,
                                                 S + (size_t)i * N);
        xb = hbb + (size_t)i * NF;
    }

    // attention + fc + log_softmax (bf16 h input, f32 math)
    k_attn_final<<<(N + 63) / 64, 256, 0, stream>>>(hbb, S, fs, att_b, fc_w, fc_b, out);
}